// Round 6
// baseline (636.691 us; speedup 1.0000x reference)
//
#include <hip/hip_runtime.h>

#define N_NODES 100000
#define N_EDGES 1600000

__device__ __forceinline__ float bflo(unsigned int u) { return __uint_as_float(u << 16); }
__device__ __forceinline__ float bfhi(unsigned int u) { return __uint_as_float(u & 0xffff0000u); }
__device__ __forceinline__ float bf2f(unsigned short u) {
    return __uint_as_float(((unsigned int)u) << 16);
}
__device__ __forceinline__ unsigned short f2bf(float f) {
    unsigned int u = __float_as_uint(f);
    unsigned int r = (u + 0x7fffu + ((u >> 16) & 1u)) >> 16;   // round-to-nearest-even
    return (unsigned short)r;
}

// ================= CSR build =================
__global__ __launch_bounds__(256) void k_hist(const int* __restrict__ dst, int* __restrict__ deg) {
    int e = blockIdx.x * 256 + threadIdx.x;
    if (e < N_EDGES) atomicAdd(&deg[dst[e]], 1);
}

__global__ __launch_bounds__(1024) void k_part_scan(const int* __restrict__ deg,
                                                    int* __restrict__ rowstart, int* __restrict__ bsum) {
    __shared__ int wsum[16];
    const int tid = threadIdx.x, lane = tid & 63, wid = tid >> 6;
    int i = blockIdx.x * 1024 + tid;
    int v = (i < N_NODES) ? deg[i] : 0;
    int s = v;
    #pragma unroll
    for (int off = 1; off < 64; off <<= 1) {
        int t = __shfl_up(s, off);
        if (lane >= off) s += t;
    }
    if (lane == 63) wsum[wid] = s;
    __syncthreads();
    if (tid < 16) {
        int w = wsum[tid];
        #pragma unroll
        for (int off = 1; off < 16; off <<= 1) {
            int t = __shfl_up(w, off);
            if (tid >= off) w += t;
        }
        wsum[tid] = w;
    }
    __syncthreads();
    int wexcl = (wid == 0) ? 0 : wsum[wid - 1];
    if (i < N_NODES) rowstart[i] = wexcl + s - v;
    if (tid == 1023) bsum[blockIdx.x] = wexcl + s;
}

__global__ __launch_bounds__(128) void k_scan_bsum(const int* __restrict__ bsum, int* __restrict__ boff,
                                                   int* __restrict__ rowstart, int nblk) {
    __shared__ int sh[128];
    int t = threadIdx.x;
    int v = (t < nblk) ? bsum[t] : 0;
    int acc = v;
    sh[t] = acc;
    __syncthreads();
    #pragma unroll
    for (int off = 1; off < 128; off <<= 1) {
        int add = (t >= off) ? sh[t - off] : 0;
        __syncthreads();
        acc += add;
        sh[t] = acc;
        __syncthreads();
    }
    if (t < nblk) boff[t] = acc - v;
    if (t == nblk - 1) rowstart[N_NODES] = acc;
}

__global__ __launch_bounds__(1024) void k_add_off(const int* __restrict__ boff, int* __restrict__ rowstart) {
    int i = blockIdx.x * 1024 + threadIdx.x;
    if (i < N_NODES) rowstart[i] += boff[blockIdx.x];
}

__global__ __launch_bounds__(256) void k_fill(const int* __restrict__ src, const int* __restrict__ dst,
                                             int* __restrict__ cursor, int* __restrict__ srcs_sorted) {
    int e = blockIdx.x * 256 + threadIdx.x;
    if (e < N_EDGES) {
        int d = dst[e];
        int p = atomicAdd(&cursor[d], 1);
        srcs_sorted[p] = src[e];
    }
}

// ================= cast x to bf16 (message copy) =================
__global__ __launch_bounds__(256) void k_cast_x(const float* __restrict__ x, unsigned short* __restrict__ xh) {
    int i = blockIdx.x * 256 + threadIdx.x;     // 1.6M threads, 4 elems each
    float4 v = *reinterpret_cast<const float4*>(x + (size_t)i * 4);
    ushort4 o;
    o.x = f2bf(v.x); o.y = f2bf(v.y); o.z = f2bf(v.z); o.w = f2bf(v.w);
    *reinterpret_cast<ushort4*>(xh + (size_t)i * 4) = o;
}

// ================= layer 1: gather(bf16, unroll-8) + dense + relu -> bf16 h1h =================
// 512 threads (8 waves), 32-node tile, wave gathers 4 nodes.
__global__ __launch_bounds__(512, 8) void k_layer1(
    const float* __restrict__ x, const unsigned short* __restrict__ xh,
    const int* __restrict__ rowstart, const int* __restrict__ srcs,
    const float* __restrict__ Wl, const float* __restrict__ Wr, const float* __restrict__ b,
    unsigned short* __restrict__ h1h)
{
    __shared__ float la[32][68];
    __shared__ float lx[32][68];
    __shared__ int rs[33];
    const int tile = blockIdx.x * 32;          // 100000 = 3125*32
    const int tid = threadIdx.x, lane = tid & 63, wid = tid >> 6;

    if (tid < 33) rs[tid] = rowstart[tile + tid];
    {   // stage root rows (f32): 32 nodes x 64 = 2048 f32, one float4 per thread
        int node = tid >> 4, k = (tid & 15) * 4;
        float4 v = *reinterpret_cast<const float4*>(x + (size_t)(tile + node) * 64 + k);
        *reinterpret_cast<float4*>(&lx[node][k]) = v;
    }
    __syncthreads();

    #pragma unroll
    for (int it = 0; it < 4; ++it) {
        int node = wid * 4 + it;
        int e0 = rs[node], e1 = rs[node + 1];
        float a0 = 0.f, a1 = 0.f, a2 = 0.f, a3 = 0.f;
        int e = e0;
        for (; e + 8 <= e1; e += 8) {
            int s0 = srcs[e],     s1 = srcs[e + 1], s2 = srcs[e + 2], s3 = srcs[e + 3];
            int s4 = srcs[e + 4], s5 = srcs[e + 5], s6 = srcs[e + 6], s7 = srcs[e + 7];
            float v0 = bf2f(xh[(size_t)s0 * 64 + lane]);
            float v1 = bf2f(xh[(size_t)s1 * 64 + lane]);
            float v2 = bf2f(xh[(size_t)s2 * 64 + lane]);
            float v3 = bf2f(xh[(size_t)s3 * 64 + lane]);
            float v4 = bf2f(xh[(size_t)s4 * 64 + lane]);
            float v5 = bf2f(xh[(size_t)s5 * 64 + lane]);
            float v6 = bf2f(xh[(size_t)s6 * 64 + lane]);
            float v7 = bf2f(xh[(size_t)s7 * 64 + lane]);
            a0 += v0; a1 += v1; a2 += v2; a3 += v3;
            a0 += v4; a1 += v5; a2 += v6; a3 += v7;
        }
        for (; e < e1; ++e)
            a0 += bf2f(xh[(size_t)srcs[e] * 64 + lane]);
        float acc = (a0 + a1) + (a2 + a3);
        int d = e1 - e0;
        la[node][lane] = acc * ((d > 0) ? (1.0f / (float)d) : 1.0f);
    }
    __syncthreads();

    const int jg = tid & 31, ng = tid >> 5;     // 32 col-groups x 16 node-groups
    const int j4 = jg * 4, nb = ng * 2;
    float acc[2][4] = {};
    for (int k = 0; k < 64; ++k) {
        float4 w1 = *reinterpret_cast<const float4*>(Wl + k * 128 + j4);
        float4 w2 = *reinterpret_cast<const float4*>(Wr + k * 128 + j4);
        #pragma unroll
        for (int i = 0; i < 2; ++i) {
            float a = la[nb + i][k], xx = lx[nb + i][k];
            acc[i][0] += a * w1.x + xx * w2.x;
            acc[i][1] += a * w1.y + xx * w2.y;
            acc[i][2] += a * w1.z + xx * w2.z;
            acc[i][3] += a * w1.w + xx * w2.w;
        }
    }
    float4 bb = *reinterpret_cast<const float4*>(b + j4);
    #pragma unroll
    for (int i = 0; i < 2; ++i) {
        int n = tile + nb + i;
        ushort4 oh;
        oh.x = f2bf(fmaxf(acc[i][0] + bb.x, 0.0f));
        oh.y = f2bf(fmaxf(acc[i][1] + bb.y, 0.0f));
        oh.z = f2bf(fmaxf(acc[i][2] + bb.z, 0.0f));
        oh.w = f2bf(fmaxf(acc[i][3] + bb.w, 0.0f));
        *reinterpret_cast<ushort4*>(h1h + (size_t)n * 128 + j4) = oh;
    }
}

// ================= layer 2 + heads: gather(bf16x2, unroll-8) + dense + relu + heads =================
// 512 threads (8 waves), 32-node tile; root rows staged packed-bf16 to keep LDS small.
__global__ __launch_bounds__(512, 8) void k_layer2(
    const unsigned int* __restrict__ h1h32,
    const int* __restrict__ rowstart, const int* __restrict__ srcs,
    const float* __restrict__ Wl, const float* __restrict__ Wr, const float* __restrict__ b,
    const float* __restrict__ Wh, const float* __restrict__ bh,
    const float* __restrict__ Wm, const float* __restrict__ bm,
    float* __restrict__ out1, float* __restrict__ out2)
{
    __shared__ float la[32][132];               // aggregated rows (f32), later h2
    __shared__ unsigned int lhp[32][68];        // root rows, packed bf16x2
    __shared__ int rs[33];
    const int tile = blockIdx.x * 32;
    const int tid = threadIdx.x, lane = tid & 63, wid = tid >> 6;

    if (tid < 33) rs[tid] = rowstart[tile + tid];
    {   // stage root rows: 32 nodes x 64 u32, one uint4 per thread
        int node = tid >> 4, c = (tid & 15) * 4;
        uint4 v = *reinterpret_cast<const uint4*>(h1h32 + (size_t)(tile + node) * 64 + c);
        *reinterpret_cast<uint4*>(&lhp[node][c]) = v;
    }
    __syncthreads();

    #pragma unroll
    for (int it = 0; it < 4; ++it) {
        int node = wid * 4 + it;
        int e0 = rs[node], e1 = rs[node + 1];
        float ax0 = 0.f, ax1 = 0.f, ax2 = 0.f, ax3 = 0.f;
        float ay0 = 0.f, ay1 = 0.f, ay2 = 0.f, ay3 = 0.f;
        int e = e0;
        for (; e + 8 <= e1; e += 8) {
            int s0 = srcs[e],     s1 = srcs[e + 1], s2 = srcs[e + 2], s3 = srcs[e + 3];
            int s4 = srcs[e + 4], s5 = srcs[e + 5], s6 = srcs[e + 6], s7 = srcs[e + 7];
            unsigned int u0 = h1h32[(size_t)s0 * 64 + lane];
            unsigned int u1 = h1h32[(size_t)s1 * 64 + lane];
            unsigned int u2 = h1h32[(size_t)s2 * 64 + lane];
            unsigned int u3 = h1h32[(size_t)s3 * 64 + lane];
            unsigned int u4 = h1h32[(size_t)s4 * 64 + lane];
            unsigned int u5 = h1h32[(size_t)s5 * 64 + lane];
            unsigned int u6 = h1h32[(size_t)s6 * 64 + lane];
            unsigned int u7 = h1h32[(size_t)s7 * 64 + lane];
            ax0 += bflo(u0); ay0 += bfhi(u0);
            ax1 += bflo(u1); ay1 += bfhi(u1);
            ax2 += bflo(u2); ay2 += bfhi(u2);
            ax3 += bflo(u3); ay3 += bfhi(u3);
            ax0 += bflo(u4); ay0 += bfhi(u4);
            ax1 += bflo(u5); ay1 += bfhi(u5);
            ax2 += bflo(u6); ay2 += bfhi(u6);
            ax3 += bflo(u7); ay3 += bfhi(u7);
        }
        for (; e < e1; ++e) {
            unsigned int u = h1h32[(size_t)srcs[e] * 64 + lane];
            ax0 += bflo(u); ay0 += bfhi(u);
        }
        float ax = (ax0 + ax1) + (ax2 + ax3);
        float ay = (ay0 + ay1) + (ay2 + ay3);
        int d = e1 - e0;
        float rd = (d > 0) ? (1.0f / (float)d) : 1.0f;
        float2 o; o.x = ax * rd; o.y = ay * rd;
        *reinterpret_cast<float2*>(&la[node][lane * 2]) = o;
    }
    __syncthreads();

    const int jg = tid & 31, ng = tid >> 5;
    const int j4 = jg * 4, nb = ng * 2;
    float acc[2][4] = {};
    for (int kp = 0; kp < 64; ++kp) {
        int k0 = kp * 2;
        float4 w1a = *reinterpret_cast<const float4*>(Wl + k0 * 128 + j4);
        float4 w2a = *reinterpret_cast<const float4*>(Wr + k0 * 128 + j4);
        float4 w1b = *reinterpret_cast<const float4*>(Wl + (k0 + 1) * 128 + j4);
        float4 w2b = *reinterpret_cast<const float4*>(Wr + (k0 + 1) * 128 + j4);
        #pragma unroll
        for (int i = 0; i < 2; ++i) {
            unsigned int u = lhp[nb + i][kp];
            float h0 = bflo(u), h1v = bfhi(u);
            float a0 = la[nb + i][k0], a1 = la[nb + i][k0 + 1];
            acc[i][0] += a0 * w1a.x + h0 * w2a.x + a1 * w1b.x + h1v * w2b.x;
            acc[i][1] += a0 * w1a.y + h0 * w2a.y + a1 * w1b.y + h1v * w2b.y;
            acc[i][2] += a0 * w1a.z + h0 * w2a.z + a1 * w1b.z + h1v * w2b.z;
            acc[i][3] += a0 * w1a.w + h0 * w2a.w + a1 * w1b.w + h1v * w2b.w;
        }
    }
    __syncthreads();   // everyone done reading la before overwrite with h2

    float4 bb = *reinterpret_cast<const float4*>(b + j4);
    #pragma unroll
    for (int i = 0; i < 2; ++i) {
        float4 o;
        o.x = fmaxf(acc[i][0] + bb.x, 0.0f);
        o.y = fmaxf(acc[i][1] + bb.y, 0.0f);
        o.z = fmaxf(acc[i][2] + bb.z, 0.0f);
        o.w = fmaxf(acc[i][3] + bb.w, 0.0f);
        *reinterpret_cast<float4*>(&la[nb + i][j4]) = o;   // h2 tile into LDS
    }
    __syncthreads();

    if (tid < 352) {
        int node = tid / 11, o = tid - node * 11;
        const float* h2 = &la[node][0];
        if (o < 3) {
            float s = bh[o];
            for (int k = 0; k < 128; ++k) s += h2[k] * Wh[k * 3 + o];
            out1[(size_t)(tile + node) * 3 + o] = s;
        } else {
            int m = o - 3;
            float s = bm[m];
            for (int k = 0; k < 128; ++k) s += h2[k] * Wm[k * 8 + m];
            out2[(size_t)(tile + node) * 8 + m] = s;
        }
    }
}

extern "C" void kernel_launch(void* const* d_in, const int* in_sizes, int n_in,
                              void* d_out, int out_size, void* d_ws, size_t ws_size,
                              hipStream_t stream) {
    const float* x   = (const float*)d_in[0];
    const int*   ei  = (const int*)d_in[1];
    const int*   src = ei;
    const int*   dst = ei + N_EDGES;
    const float* Wl1 = (const float*)d_in[2];
    const float* Wr1 = (const float*)d_in[3];
    const float* b1  = (const float*)d_in[4];
    const float* Wl2 = (const float*)d_in[5];
    const float* Wr2 = (const float*)d_in[6];
    const float* b2  = (const float*)d_in[7];
    const float* Wh  = (const float*)d_in[8];
    const float* bh  = (const float*)d_in[9];
    const float* Wm  = (const float*)d_in[10];
    const float* bm  = (const float*)d_in[11];

    float* out1 = (float*)d_out;                   // [N,3]
    float* out2 = out1 + (size_t)N_NODES * 3;      // [N,8]

    char* ws = (char*)d_ws;
    int*   deg      = (int*)(ws);                          // 100000 ints
    int*   rowstart = (int*)(ws + (512 << 10));            // 100001 ints
    int*   cursor   = (int*)(ws + (1024 << 10));           // 100000 ints
    int*   bsum     = (int*)(ws + (1408 << 10));           // 98 ints
    int*   boff     = (int*)(ws + (1472 << 10));           // 98 ints
    int*   srcs     = (int*)(ws + (1536 << 10));           // 1.6M ints (6.4MB)
    unsigned short* xh  = (unsigned short*)(ws + (8192 << 10));   // 6.4M bf16 (12.8MB)
    unsigned short* h1h = (unsigned short*)(ws + (21504 << 10)); // 12.8M bf16 (25.6MB)

    const int NSCAN = (N_NODES + 1023) / 1024;             // 98

    k_cast_x<<<6250, 256, 0, stream>>>(x, xh);
    hipMemsetAsync(deg, 0, N_NODES * sizeof(int), stream);
    k_hist<<<6250, 256, 0, stream>>>(dst, deg);
    k_part_scan<<<NSCAN, 1024, 0, stream>>>(deg, rowstart, bsum);
    k_scan_bsum<<<1, 128, 0, stream>>>(bsum, boff, rowstart, NSCAN);
    k_add_off<<<NSCAN, 1024, 0, stream>>>(boff, rowstart);
    hipMemcpyAsync(cursor, rowstart, N_NODES * sizeof(int), hipMemcpyDeviceToDevice, stream);
    k_fill<<<6250, 256, 0, stream>>>(src, dst, cursor, srcs);

    k_layer1<<<3125, 512, 0, stream>>>(x, xh, rowstart, srcs, Wl1, Wr1, b1, h1h);
    k_layer2<<<3125, 512, 0, stream>>>((const unsigned int*)h1h, rowstart, srcs,
                                       Wl2, Wr2, b2, Wh, bh, Wm, bm, out1, out2);
}

// Round 7
// 397.423 us; speedup vs baseline: 1.6021x; 1.6021x over previous
//
#include <hip/hip_runtime.h>

#define N_NODES 100000
#define N_EDGES 1600000

typedef __attribute__((ext_vector_type(8))) short short8;
typedef __attribute__((ext_vector_type(4))) float f32x4;

__device__ __forceinline__ float bflo(unsigned int u) { return __uint_as_float(u << 16); }
__device__ __forceinline__ float bfhi(unsigned int u) { return __uint_as_float(u & 0xffff0000u); }
__device__ __forceinline__ float bf2f(unsigned short u) { return __uint_as_float(((unsigned int)u) << 16); }
__device__ __forceinline__ unsigned short f2bf(float f) {
    unsigned int u = __float_as_uint(f);
    return (unsigned short)((u + 0x7fffu + ((u >> 16) & 1u)) >> 16);   // RNE
}

// ================= fused cast x->bf16 + degree histogram =================
__global__ __launch_bounds__(256) void k_cast_hist(const float* __restrict__ x, unsigned short* __restrict__ xh,
                                                   const int* __restrict__ dst, int* __restrict__ deg) {
    int i = blockIdx.x * 256 + threadIdx.x;     // 1.6M threads: 4 x-elems + 1 edge each
    float4 v = *reinterpret_cast<const float4*>(x + (size_t)i * 4);
    ushort4 o;
    o.x = f2bf(v.x); o.y = f2bf(v.y); o.z = f2bf(v.z); o.w = f2bf(v.w);
    *reinterpret_cast<ushort4*>(xh + (size_t)i * 4) = o;
    atomicAdd(&deg[dst[i]], 1);
}

// ================= CSR scan chain =================
__global__ __launch_bounds__(1024) void k_part_scan(const int* __restrict__ deg,
                                                    int* __restrict__ rowstart, int* __restrict__ bsum) {
    __shared__ int wsum[16];
    const int tid = threadIdx.x, lane = tid & 63, wid = tid >> 6;
    int i = blockIdx.x * 1024 + tid;
    int v = (i < N_NODES) ? deg[i] : 0;
    int s = v;
    #pragma unroll
    for (int off = 1; off < 64; off <<= 1) {
        int t = __shfl_up(s, off);
        if (lane >= off) s += t;
    }
    if (lane == 63) wsum[wid] = s;
    __syncthreads();
    if (tid < 16) {
        int w = wsum[tid];
        #pragma unroll
        for (int off = 1; off < 16; off <<= 1) {
            int t = __shfl_up(w, off);
            if (tid >= off) w += t;
        }
        wsum[tid] = w;
    }
    __syncthreads();
    int wexcl = (wid == 0) ? 0 : wsum[wid - 1];
    if (i < N_NODES) rowstart[i] = wexcl + s - v;
    if (tid == 1023) bsum[blockIdx.x] = wexcl + s;
}

__global__ __launch_bounds__(128) void k_scan_bsum(const int* __restrict__ bsum, int* __restrict__ boff,
                                                   int* __restrict__ rowstart, int nblk) {
    __shared__ int sh[128];
    int t = threadIdx.x;
    int v = (t < nblk) ? bsum[t] : 0;
    int acc = v;
    sh[t] = acc;
    __syncthreads();
    #pragma unroll
    for (int off = 1; off < 128; off <<= 1) {
        int add = (t >= off) ? sh[t - off] : 0;
        __syncthreads();
        acc += add;
        sh[t] = acc;
        __syncthreads();
    }
    if (t < nblk) boff[t] = acc - v;
    if (t == nblk - 1) rowstart[N_NODES] = acc;
}

__global__ __launch_bounds__(1024) void k_add_off(const int* __restrict__ boff, int* __restrict__ rowstart) {
    int i = blockIdx.x * 1024 + threadIdx.x;
    if (i < N_NODES) rowstart[i] += boff[blockIdx.x];
}

__global__ __launch_bounds__(256) void k_fill(const int* __restrict__ src, const int* __restrict__ dst,
                                             int* __restrict__ cursor, int* __restrict__ srcs_sorted) {
    int e = blockIdx.x * 256 + threadIdx.x;
    if (e < N_EDGES) {
        int d = dst[e];
        int p = atomicAdd(&cursor[d], 1);
        srcs_sorted[p] = src[e];
    }
}

// ================= weight prepack into MFMA fragment order (bf16) =================
// Bp[((kk*128 + col)*4 + g)*8 + j] = W[kk*32 + g*8 + j][col]; W = [Wl ; Wr] stacked on K.
__global__ __launch_bounds__(256) void k_pack(const float* __restrict__ Wl1, const float* __restrict__ Wr1,
                                              const float* __restrict__ Wl2, const float* __restrict__ Wr2,
                                              unsigned short* __restrict__ Bp1, unsigned short* __restrict__ Bp2) {
    int idx = blockIdx.x * 256 + threadIdx.x;   // 49152 threads
    if (idx < 16384) {                          // layer1: K=128
        int j = idx & 7, g = (idx >> 3) & 3, col = (idx >> 5) & 127, kk = idx >> 12;
        int r = kk * 32 + g * 8 + j;
        float w = (r < 64) ? Wl1[r * 128 + col] : Wr1[(r - 64) * 128 + col];
        Bp1[idx] = f2bf(w);
    } else {                                    // layer2: K=256
        int q = idx - 16384;
        int j = q & 7, g = (q >> 3) & 3, col = (q >> 5) & 127, kk = q >> 12;
        int r = kk * 32 + g * 8 + j;
        float w = (r < 128) ? Wl2[r * 128 + col] : Wr2[(r - 128) * 128 + col];
        Bp2[q] = f2bf(w);
    }
}

// ================= layer 1: gather(bf16) + MFMA dense + relu -> bf16 h1h =================
// 256 threads, 32-node tile. A = [32 x 128] bf16 in LDS: cols 0..63 = mean-agg, 64..127 = root.
__global__ __launch_bounds__(256, 8) void k_layer1(
    const unsigned short* __restrict__ xh,
    const int* __restrict__ rowstart, const int* __restrict__ srcs,
    const unsigned short* __restrict__ Bp1, const float* __restrict__ b,
    unsigned short* __restrict__ h1h)
{
    __shared__ unsigned short A[32][136];       // +8 pad: 272B row stride, 2-way bank alias (free)
    __shared__ int rs[33];
    const int tile = blockIdx.x * 32;           // 100000 = 3125*32
    const int tid = threadIdx.x, lane = tid & 63, wid = tid >> 6;

    if (tid < 33) rs[tid] = rowstart[tile + tid];
    {   // root rows -> cols 64..127 (already bf16): 8 threads/node, 16B each
        int node = tid >> 3, part = tid & 7;
        uint4 v = *reinterpret_cast<const uint4*>(xh + (size_t)(tile + node) * 64 + part * 8);
        *reinterpret_cast<uint4*>(&A[node][64 + part * 8]) = v;
    }
    __syncthreads();

    for (int it = 0; it < 8; ++it) {            // wave-per-node gather, unroll-8
        int nl = wid * 8 + it;
        int e0 = rs[nl], e1 = rs[nl + 1];
        float a0 = 0.f, a1 = 0.f, a2 = 0.f, a3 = 0.f;
        int e = e0;
        for (; e + 8 <= e1; e += 8) {
            int s0 = srcs[e],     s1 = srcs[e + 1], s2 = srcs[e + 2], s3 = srcs[e + 3];
            int s4 = srcs[e + 4], s5 = srcs[e + 5], s6 = srcs[e + 6], s7 = srcs[e + 7];
            float v0 = bf2f(xh[(size_t)s0 * 64 + lane]);
            float v1 = bf2f(xh[(size_t)s1 * 64 + lane]);
            float v2 = bf2f(xh[(size_t)s2 * 64 + lane]);
            float v3 = bf2f(xh[(size_t)s3 * 64 + lane]);
            float v4 = bf2f(xh[(size_t)s4 * 64 + lane]);
            float v5 = bf2f(xh[(size_t)s5 * 64 + lane]);
            float v6 = bf2f(xh[(size_t)s6 * 64 + lane]);
            float v7 = bf2f(xh[(size_t)s7 * 64 + lane]);
            a0 += v0; a1 += v1; a2 += v2; a3 += v3;
            a0 += v4; a1 += v5; a2 += v6; a3 += v7;
        }
        for (; e < e1; ++e)
            a0 += bf2f(xh[(size_t)srcs[e] * 64 + lane]);
        float acc = (a0 + a1) + (a2 + a3);
        int d = e1 - e0;
        A[nl][lane] = f2bf(acc * ((d > 0) ? (1.0f / (float)d) : 1.0f));
    }
    __syncthreads();

    // MFMA: [32 x 128] @ [128 x 128], wave w owns cols n0..n0+31
    const int r15 = lane & 15, g4 = lane >> 4;
    const int n0 = wid * 32;
    f32x4 acc[2][2] = {};
    for (int kk = 0; kk < 4; ++kk) {
        short8 b0 = *reinterpret_cast<const short8*>(Bp1 + (((kk * 128 + n0 + r15) * 4 + g4) << 3));
        short8 b1 = *reinterpret_cast<const short8*>(Bp1 + (((kk * 128 + n0 + 16 + r15) * 4 + g4) << 3));
        #pragma unroll
        for (int mt = 0; mt < 2; ++mt) {
            short8 a = *reinterpret_cast<const short8*>(&A[mt * 16 + r15][kk * 32 + g4 * 8]);
            acc[mt][0] = __builtin_amdgcn_mfma_f32_16x16x32_bf16(a, b0, acc[mt][0], 0, 0, 0);
            acc[mt][1] = __builtin_amdgcn_mfma_f32_16x16x32_bf16(a, b1, acc[mt][1], 0, 0, 0);
        }
    }
    #pragma unroll
    for (int mt = 0; mt < 2; ++mt)
        #pragma unroll
        for (int nt = 0; nt < 2; ++nt) {
            int col = n0 + nt * 16 + r15;
            float bb = b[col];
            #pragma unroll
            for (int reg = 0; reg < 4; ++reg) {
                int row = tile + mt * 16 + g4 * 4 + reg;
                h1h[(size_t)row * 128 + col] = f2bf(fmaxf(acc[mt][nt][reg] + bb, 0.0f));
            }
        }
}

// ================= layer 2 + heads: gather(bf16x2) + MFMA dense + relu + heads =================
// A = [32 x 256] bf16 in LDS: cols 0..127 = mean-agg(h1), 128..255 = root h1.
__global__ __launch_bounds__(256, 8) void k_layer2(
    const unsigned int* __restrict__ h1h32,
    const int* __restrict__ rowstart, const int* __restrict__ srcs,
    const unsigned short* __restrict__ Bp2, const float* __restrict__ b,
    const float* __restrict__ Wh, const float* __restrict__ bh,
    const float* __restrict__ Wm, const float* __restrict__ bm,
    float* __restrict__ out1, float* __restrict__ out2)
{
    __shared__ unsigned short A[32][264];       // 528B row stride; reused as f32 h2 [32][132] later
    __shared__ int rs[33];
    const int tile = blockIdx.x * 32;
    const int tid = threadIdx.x, lane = tid & 63, wid = tid >> 6;

    if (tid < 33) rs[tid] = rowstart[tile + tid];
    {   // root rows -> cols 128..255: 8 threads/node, 2x16B each
        int node = tid >> 3, part = tid & 7;
        const unsigned int* p = h1h32 + (size_t)(tile + node) * 64 + part * 8;
        uint4 v0 = *reinterpret_cast<const uint4*>(p);
        uint4 v1 = *reinterpret_cast<const uint4*>(p + 4);
        *reinterpret_cast<uint4*>(&A[node][128 + part * 16]) = v0;
        *reinterpret_cast<uint4*>(&A[node][128 + part * 16 + 8]) = v1;
    }
    __syncthreads();

    for (int it = 0; it < 8; ++it) {            // wave-per-node gather, unroll-8, u32 = 2 bf16 cols
        int nl = wid * 8 + it;
        int e0 = rs[nl], e1 = rs[nl + 1];
        float ax0 = 0.f, ax1 = 0.f, ax2 = 0.f, ax3 = 0.f;
        float ay0 = 0.f, ay1 = 0.f, ay2 = 0.f, ay3 = 0.f;
        int e = e0;
        for (; e + 8 <= e1; e += 8) {
            int s0 = srcs[e],     s1 = srcs[e + 1], s2 = srcs[e + 2], s3 = srcs[e + 3];
            int s4 = srcs[e + 4], s5 = srcs[e + 5], s6 = srcs[e + 6], s7 = srcs[e + 7];
            unsigned int u0 = h1h32[(size_t)s0 * 64 + lane];
            unsigned int u1 = h1h32[(size_t)s1 * 64 + lane];
            unsigned int u2 = h1h32[(size_t)s2 * 64 + lane];
            unsigned int u3 = h1h32[(size_t)s3 * 64 + lane];
            unsigned int u4 = h1h32[(size_t)s4 * 64 + lane];
            unsigned int u5 = h1h32[(size_t)s5 * 64 + lane];
            unsigned int u6 = h1h32[(size_t)s6 * 64 + lane];
            unsigned int u7 = h1h32[(size_t)s7 * 64 + lane];
            ax0 += bflo(u0); ay0 += bfhi(u0);
            ax1 += bflo(u1); ay1 += bfhi(u1);
            ax2 += bflo(u2); ay2 += bfhi(u2);
            ax3 += bflo(u3); ay3 += bfhi(u3);
            ax0 += bflo(u4); ay0 += bfhi(u4);
            ax1 += bflo(u5); ay1 += bfhi(u5);
            ax2 += bflo(u6); ay2 += bfhi(u6);
            ax3 += bflo(u7); ay3 += bfhi(u7);
        }
        for (; e < e1; ++e) {
            unsigned int u = h1h32[(size_t)srcs[e] * 64 + lane];
            ax0 += bflo(u); ay0 += bfhi(u);
        }
        float ax = (ax0 + ax1) + (ax2 + ax3);
        float ay = (ay0 + ay1) + (ay2 + ay3);
        int d = e1 - e0;
        float rd = (d > 0) ? (1.0f / (float)d) : 1.0f;
        unsigned int p = (unsigned int)f2bf(ax * rd) | ((unsigned int)f2bf(ay * rd) << 16);
        *reinterpret_cast<unsigned int*>(&A[nl][2 * lane]) = p;   // cols 2*lane, 2*lane+1
    }
    __syncthreads();

    // MFMA: [32 x 256] @ [256 x 128]
    const int r15 = lane & 15, g4 = lane >> 4;
    const int n0 = wid * 32;
    f32x4 acc[2][2] = {};
    for (int kk = 0; kk < 8; ++kk) {
        short8 b0 = *reinterpret_cast<const short8*>(Bp2 + (((kk * 128 + n0 + r15) * 4 + g4) << 3));
        short8 b1 = *reinterpret_cast<const short8*>(Bp2 + (((kk * 128 + n0 + 16 + r15) * 4 + g4) << 3));
        #pragma unroll
        for (int mt = 0; mt < 2; ++mt) {
            short8 a = *reinterpret_cast<const short8*>(&A[mt * 16 + r15][kk * 32 + g4 * 8]);
            acc[mt][0] = __builtin_amdgcn_mfma_f32_16x16x32_bf16(a, b0, acc[mt][0], 0, 0, 0);
            acc[mt][1] = __builtin_amdgcn_mfma_f32_16x16x32_bf16(a, b1, acc[mt][1], 0, 0, 0);
        }
    }
    __syncthreads();                             // all waves done reading A -> reuse as f32 h2
    float* h2L = reinterpret_cast<float*>(&A[0][0]);   // [32][132]
    #pragma unroll
    for (int mt = 0; mt < 2; ++mt)
        #pragma unroll
        for (int nt = 0; nt < 2; ++nt) {
            int col = n0 + nt * 16 + r15;
            float bb = b[col];
            #pragma unroll
            for (int reg = 0; reg < 4; ++reg) {
                int row = mt * 16 + g4 * 4 + reg;
                h2L[row * 132 + col] = fmaxf(acc[mt][nt][reg] + bb, 0.0f);
            }
        }
    __syncthreads();

    for (int t = tid; t < 352; t += 256) {       // heads: 32 nodes x (3+8)
        int node = t / 11, o = t - node * 11;
        const float* h2 = &h2L[node * 132];
        if (o < 3) {
            float s = bh[o];
            for (int k = 0; k < 128; ++k) s += h2[k] * Wh[k * 3 + o];
            out1[(size_t)(tile + node) * 3 + o] = s;
        } else {
            int m = o - 3;
            float s = bm[m];
            for (int k = 0; k < 128; ++k) s += h2[k] * Wm[k * 8 + m];
            out2[(size_t)(tile + node) * 8 + m] = s;
        }
    }
}

extern "C" void kernel_launch(void* const* d_in, const int* in_sizes, int n_in,
                              void* d_out, int out_size, void* d_ws, size_t ws_size,
                              hipStream_t stream) {
    const float* x   = (const float*)d_in[0];
    const int*   ei  = (const int*)d_in[1];
    const int*   src = ei;
    const int*   dst = ei + N_EDGES;
    const float* Wl1 = (const float*)d_in[2];
    const float* Wr1 = (const float*)d_in[3];
    const float* b1  = (const float*)d_in[4];
    const float* Wl2 = (const float*)d_in[5];
    const float* Wr2 = (const float*)d_in[6];
    const float* b2  = (const float*)d_in[7];
    const float* Wh  = (const float*)d_in[8];
    const float* bh  = (const float*)d_in[9];
    const float* Wm  = (const float*)d_in[10];
    const float* bm  = (const float*)d_in[11];

    float* out1 = (float*)d_out;                   // [N,3]
    float* out2 = out1 + (size_t)N_NODES * 3;      // [N,8]

    char* ws = (char*)d_ws;
    int*   deg      = (int*)(ws);                          // 100000 ints
    int*   rowstart = (int*)(ws + (512 << 10));            // 100001 ints
    int*   cursor   = (int*)(ws + (1024 << 10));           // 100000 ints
    int*   bsum     = (int*)(ws + (1408 << 10));           // 98 ints
    int*   boff     = (int*)(ws + (1472 << 10));           // 98 ints
    int*   srcs     = (int*)(ws + (1536 << 10));           // 1.6M ints (6.4MB)
    unsigned short* xh  = (unsigned short*)(ws + (8192 << 10));   // 6.4M bf16 (12.8MB)
    unsigned short* h1h = (unsigned short*)(ws + (21504 << 10)); // 12.8M bf16 (25.6MB)
    unsigned short* Bp1 = (unsigned short*)(ws + (47616 << 10)); // 16384 bf16 (32KB)
    unsigned short* Bp2 = (unsigned short*)(ws + (47680 << 10)); // 32768 bf16 (64KB)

    const int NSCAN = (N_NODES + 1023) / 1024;             // 98

    hipMemsetAsync(deg, 0, N_NODES * sizeof(int), stream);
    k_cast_hist<<<6250, 256, 0, stream>>>(x, xh, dst, deg);
    k_part_scan<<<NSCAN, 1024, 0, stream>>>(deg, rowstart, bsum);
    k_scan_bsum<<<1, 128, 0, stream>>>(bsum, boff, rowstart, NSCAN);
    k_add_off<<<NSCAN, 1024, 0, stream>>>(boff, rowstart);
    hipMemcpyAsync(cursor, rowstart, N_NODES * sizeof(int), hipMemcpyDeviceToDevice, stream);
    k_fill<<<6250, 256, 0, stream>>>(src, dst, cursor, srcs);
    k_pack<<<192, 256, 0, stream>>>(Wl1, Wr1, Wl2, Wr2, Bp1, Bp2);

    k_layer1<<<3125, 256, 0, stream>>>(xh, rowstart, srcs, Bp1, b1, h1h);
    k_layer2<<<3125, 256, 0, stream>>>((const unsigned int*)h1h, rowstart, srcs,
                                       Bp2, b2, Wh, bh, Wm, bm, out1, out2);
}

// Round 8
// 318.004 us; speedup vs baseline: 2.0021x; 1.2497x over previous
//
#include <hip/hip_runtime.h>

#define N_NODES 100000
#define N_EDGES 1600000
#define NBUCK 196      // ceil(100000/512) coarse buckets
#define BSH 9          // 512 nodes per bucket

typedef __attribute__((ext_vector_type(8))) short short8;
typedef __attribute__((ext_vector_type(4))) float f32x4;

__device__ __forceinline__ float bflo(unsigned int u) { return __uint_as_float(u << 16); }
__device__ __forceinline__ float bfhi(unsigned int u) { return __uint_as_float(u & 0xffff0000u); }
__device__ __forceinline__ float bf2f(unsigned short u) { return __uint_as_float(((unsigned int)u) << 16); }
__device__ __forceinline__ unsigned short f2bf(float f) {
    unsigned int u = __float_as_uint(f);
    return (unsigned short)((u + 0x7fffu + ((u >> 16) & 1u)) >> 16);   // RNE
}

// ================= fused cast x->bf16 + degree histogram =================
__global__ __launch_bounds__(256) void k_cast_hist(const float* __restrict__ x, unsigned short* __restrict__ xh,
                                                   const int* __restrict__ dst, int* __restrict__ deg) {
    int i = blockIdx.x * 256 + threadIdx.x;     // 1.6M threads: 4 x-elems + 1 edge each
    float4 v = *reinterpret_cast<const float4*>(x + (size_t)i * 4);
    ushort4 o;
    o.x = f2bf(v.x); o.y = f2bf(v.y); o.z = f2bf(v.z); o.w = f2bf(v.w);
    *reinterpret_cast<ushort4*>(xh + (size_t)i * 4) = o;
    atomicAdd(&deg[dst[i]], 1);
}

// ================= CSR scan chain =================
__global__ __launch_bounds__(1024) void k_part_scan(const int* __restrict__ deg,
                                                    int* __restrict__ rowstart, int* __restrict__ bsum) {
    __shared__ int wsum[16];
    const int tid = threadIdx.x, lane = tid & 63, wid = tid >> 6;
    int i = blockIdx.x * 1024 + tid;
    int v = (i < N_NODES) ? deg[i] : 0;
    int s = v;
    #pragma unroll
    for (int off = 1; off < 64; off <<= 1) {
        int t = __shfl_up(s, off);
        if (lane >= off) s += t;
    }
    if (lane == 63) wsum[wid] = s;
    __syncthreads();
    if (tid < 16) {
        int w = wsum[tid];
        #pragma unroll
        for (int off = 1; off < 16; off <<= 1) {
            int t = __shfl_up(w, off);
            if (tid >= off) w += t;
        }
        wsum[tid] = w;
    }
    __syncthreads();
    int wexcl = (wid == 0) ? 0 : wsum[wid - 1];
    if (i < N_NODES) rowstart[i] = wexcl + s - v;
    if (tid == 1023) bsum[blockIdx.x] = wexcl + s;
}

__global__ __launch_bounds__(128) void k_scan_bsum(const int* __restrict__ bsum, int* __restrict__ boff,
                                                   int* __restrict__ rowstart, int nblk) {
    __shared__ int sh[128];
    int t = threadIdx.x;
    int v = (t < nblk) ? bsum[t] : 0;
    int acc = v;
    sh[t] = acc;
    __syncthreads();
    #pragma unroll
    for (int off = 1; off < 128; off <<= 1) {
        int add = (t >= off) ? sh[t - off] : 0;
        __syncthreads();
        acc += add;
        sh[t] = acc;
        __syncthreads();
    }
    if (t < nblk) boff[t] = acc - v;
    if (t == nblk - 1) rowstart[N_NODES] = acc;
}

__global__ __launch_bounds__(1024) void k_add_off(const int* __restrict__ boff, int* __restrict__ rowstart) {
    int i = blockIdx.x * 1024 + threadIdx.x;
    if (i < N_NODES) rowstart[i] += boff[blockIdx.x];
}

__global__ __launch_bounds__(256) void k_init_ccur(const int* __restrict__ rowstart, int* __restrict__ ccur) {
    int t = threadIdx.x;
    if (t < NBUCK) ccur[t] = rowstart[t << BSH];
}

// ================= CSR build pass 1: coarse bucket (counting sort, packed pairs) =================
#define EPT 16
__global__ __launch_bounds__(256) void k_bucket(const int* __restrict__ src, const int* __restrict__ dst,
                                                int* __restrict__ ccur, unsigned int* __restrict__ pairs) {
    __shared__ int cnt[NBUCK];
    __shared__ int base[NBUCK];
    const int tid = threadIdx.x;
    const int e_base = blockIdx.x * (256 * EPT);
    for (int i = tid; i < NBUCK; i += 256) cnt[i] = 0;
    __syncthreads();
    #pragma unroll
    for (int i = 0; i < EPT; ++i) {              // phase A: local histogram
        int e = e_base + i * 256 + tid;
        if (e < N_EDGES) atomicAdd(&cnt[dst[e] >> BSH], 1);
    }
    __syncthreads();
    for (int i = tid; i < NBUCK; i += 256) {     // phase B: reserve global ranges
        int c = cnt[i];
        base[i] = (c > 0) ? atomicAdd(&ccur[i], c) : 0;
        cnt[i] = 0;
    }
    __syncthreads();
    #pragma unroll
    for (int i = 0; i < EPT; ++i) {              // phase C: grouped scatter
        int e = e_base + i * 256 + tid;
        if (e < N_EDGES) {
            int d = dst[e];
            int bkt = d >> BSH;
            int off = atomicAdd(&cnt[bkt], 1);
            pairs[base[bkt] + off] = ((unsigned int)(d & 511) << 17) | (unsigned int)src[e];
        }
    }
}

// ================= CSR build pass 2: within-bucket exact scatter (LDS cursors) =================
__global__ __launch_bounds__(256) void k_scatter_csr(const int* __restrict__ rowstart,
                                                     const unsigned int* __restrict__ pairs,
                                                     int* __restrict__ srcs) {
    __shared__ int lcur[512];
    const int c = blockIdx.x, tid = threadIdx.x;
    const int nbase = c << BSH;
    for (int i = tid; i < 512; i += 256) {
        int n = nbase + i;
        lcur[i] = (n < N_NODES) ? rowstart[n] : 0;
    }
    __syncthreads();
    int e0 = rowstart[nbase];
    int nend = nbase + 512; if (nend > N_NODES) nend = N_NODES;
    int e1 = rowstart[nend];
    for (int e = e0 + tid; e < e1; e += 256) {
        unsigned int u = pairs[e];
        int dloc = (int)(u >> 17);
        int p = atomicAdd(&lcur[dloc], 1);
        srcs[p] = (int)(u & 0x1FFFFu);
    }
}

// ================= weight prepack into MFMA fragment order (bf16) =================
__global__ __launch_bounds__(256) void k_pack(const float* __restrict__ Wl1, const float* __restrict__ Wr1,
                                              const float* __restrict__ Wl2, const float* __restrict__ Wr2,
                                              unsigned short* __restrict__ Bp1, unsigned short* __restrict__ Bp2) {
    int idx = blockIdx.x * 256 + threadIdx.x;   // 49152 threads
    if (idx < 16384) {                          // layer1: K=128
        int j = idx & 7, g = (idx >> 3) & 3, col = (idx >> 5) & 127, kk = idx >> 12;
        int r = kk * 32 + g * 8 + j;
        float w = (r < 64) ? Wl1[r * 128 + col] : Wr1[(r - 64) * 128 + col];
        Bp1[idx] = f2bf(w);
    } else {                                    // layer2: K=256
        int q = idx - 16384;
        int j = q & 7, g = (q >> 3) & 3, col = (q >> 5) & 127, kk = q >> 12;
        int r = kk * 32 + g * 8 + j;
        float w = (r < 128) ? Wl2[r * 128 + col] : Wr2[(r - 128) * 128 + col];
        Bp2[q] = f2bf(w);
    }
}

// ================= layer 1: gather(bf16) + MFMA dense + relu -> bf16 h1h =================
__global__ __launch_bounds__(256, 8) void k_layer1(
    const unsigned short* __restrict__ xh,
    const int* __restrict__ rowstart, const int* __restrict__ srcs,
    const unsigned short* __restrict__ Bp1, const float* __restrict__ b,
    unsigned short* __restrict__ h1h)
{
    __shared__ unsigned short A[32][136];
    __shared__ int rs[33];
    const int tile = blockIdx.x * 32;           // 100000 = 3125*32
    const int tid = threadIdx.x, lane = tid & 63, wid = tid >> 6;

    if (tid < 33) rs[tid] = rowstart[tile + tid];
    {   // root rows -> cols 64..127
        int node = tid >> 3, part = tid & 7;
        uint4 v = *reinterpret_cast<const uint4*>(xh + (size_t)(tile + node) * 64 + part * 8);
        *reinterpret_cast<uint4*>(&A[node][64 + part * 8]) = v;
    }
    __syncthreads();

    for (int it = 0; it < 8; ++it) {            // wave-per-node gather, unroll-8
        int nl = wid * 8 + it;
        int e0 = rs[nl], e1 = rs[nl + 1];
        float a0 = 0.f, a1 = 0.f, a2 = 0.f, a3 = 0.f;
        int e = e0;
        for (; e + 8 <= e1; e += 8) {
            int s0 = srcs[e],     s1 = srcs[e + 1], s2 = srcs[e + 2], s3 = srcs[e + 3];
            int s4 = srcs[e + 4], s5 = srcs[e + 5], s6 = srcs[e + 6], s7 = srcs[e + 7];
            float v0 = bf2f(xh[(size_t)s0 * 64 + lane]);
            float v1 = bf2f(xh[(size_t)s1 * 64 + lane]);
            float v2 = bf2f(xh[(size_t)s2 * 64 + lane]);
            float v3 = bf2f(xh[(size_t)s3 * 64 + lane]);
            float v4 = bf2f(xh[(size_t)s4 * 64 + lane]);
            float v5 = bf2f(xh[(size_t)s5 * 64 + lane]);
            float v6 = bf2f(xh[(size_t)s6 * 64 + lane]);
            float v7 = bf2f(xh[(size_t)s7 * 64 + lane]);
            a0 += v0; a1 += v1; a2 += v2; a3 += v3;
            a0 += v4; a1 += v5; a2 += v6; a3 += v7;
        }
        for (; e < e1; ++e)
            a0 += bf2f(xh[(size_t)srcs[e] * 64 + lane]);
        float acc = (a0 + a1) + (a2 + a3);
        int d = e1 - e0;
        A[nl][lane] = f2bf(acc * ((d > 0) ? (1.0f / (float)d) : 1.0f));
    }
    __syncthreads();

    const int r15 = lane & 15, g4 = lane >> 4;
    const int n0 = wid * 32;
    f32x4 acc[2][2] = {};
    for (int kk = 0; kk < 4; ++kk) {
        short8 b0 = *reinterpret_cast<const short8*>(Bp1 + (((kk * 128 + n0 + r15) * 4 + g4) << 3));
        short8 b1 = *reinterpret_cast<const short8*>(Bp1 + (((kk * 128 + n0 + 16 + r15) * 4 + g4) << 3));
        #pragma unroll
        for (int mt = 0; mt < 2; ++mt) {
            short8 a = *reinterpret_cast<const short8*>(&A[mt * 16 + r15][kk * 32 + g4 * 8]);
            acc[mt][0] = __builtin_amdgcn_mfma_f32_16x16x32_bf16(a, b0, acc[mt][0], 0, 0, 0);
            acc[mt][1] = __builtin_amdgcn_mfma_f32_16x16x32_bf16(a, b1, acc[mt][1], 0, 0, 0);
        }
    }
    #pragma unroll
    for (int mt = 0; mt < 2; ++mt)
        #pragma unroll
        for (int nt = 0; nt < 2; ++nt) {
            int col = n0 + nt * 16 + r15;
            float bb = b[col];
            #pragma unroll
            for (int reg = 0; reg < 4; ++reg) {
                int row = tile + mt * 16 + g4 * 4 + reg;
                h1h[(size_t)row * 128 + col] = f2bf(fmaxf(acc[mt][nt][reg] + bb, 0.0f));
            }
        }
}

// ================= layer 2 + heads: gather(bf16x2) + MFMA dense + relu + heads =================
__global__ __launch_bounds__(256, 8) void k_layer2(
    const unsigned int* __restrict__ h1h32,
    const int* __restrict__ rowstart, const int* __restrict__ srcs,
    const unsigned short* __restrict__ Bp2, const float* __restrict__ b,
    const float* __restrict__ Wh, const float* __restrict__ bh,
    const float* __restrict__ Wm, const float* __restrict__ bm,
    float* __restrict__ out1, float* __restrict__ out2)
{
    __shared__ unsigned short A[32][264];
    __shared__ int rs[33];
    const int tile = blockIdx.x * 32;
    const int tid = threadIdx.x, lane = tid & 63, wid = tid >> 6;

    if (tid < 33) rs[tid] = rowstart[tile + tid];
    {   // root rows -> cols 128..255
        int node = tid >> 3, part = tid & 7;
        const unsigned int* p = h1h32 + (size_t)(tile + node) * 64 + part * 8;
        uint4 v0 = *reinterpret_cast<const uint4*>(p);
        uint4 v1 = *reinterpret_cast<const uint4*>(p + 4);
        *reinterpret_cast<uint4*>(&A[node][128 + part * 16]) = v0;
        *reinterpret_cast<uint4*>(&A[node][128 + part * 16 + 8]) = v1;
    }
    __syncthreads();

    for (int it = 0; it < 8; ++it) {            // wave-per-node gather, unroll-8
        int nl = wid * 8 + it;
        int e0 = rs[nl], e1 = rs[nl + 1];
        float ax0 = 0.f, ax1 = 0.f, ax2 = 0.f, ax3 = 0.f;
        float ay0 = 0.f, ay1 = 0.f, ay2 = 0.f, ay3 = 0.f;
        int e = e0;
        for (; e + 8 <= e1; e += 8) {
            int s0 = srcs[e],     s1 = srcs[e + 1], s2 = srcs[e + 2], s3 = srcs[e + 3];
            int s4 = srcs[e + 4], s5 = srcs[e + 5], s6 = srcs[e + 6], s7 = srcs[e + 7];
            unsigned int u0 = h1h32[(size_t)s0 * 64 + lane];
            unsigned int u1 = h1h32[(size_t)s1 * 64 + lane];
            unsigned int u2 = h1h32[(size_t)s2 * 64 + lane];
            unsigned int u3 = h1h32[(size_t)s3 * 64 + lane];
            unsigned int u4 = h1h32[(size_t)s4 * 64 + lane];
            unsigned int u5 = h1h32[(size_t)s5 * 64 + lane];
            unsigned int u6 = h1h32[(size_t)s6 * 64 + lane];
            unsigned int u7 = h1h32[(size_t)s7 * 64 + lane];
            ax0 += bflo(u0); ay0 += bfhi(u0);
            ax1 += bflo(u1); ay1 += bfhi(u1);
            ax2 += bflo(u2); ay2 += bfhi(u2);
            ax3 += bflo(u3); ay3 += bfhi(u3);
            ax0 += bflo(u4); ay0 += bfhi(u4);
            ax1 += bflo(u5); ay1 += bfhi(u5);
            ax2 += bflo(u6); ay2 += bfhi(u6);
            ax3 += bflo(u7); ay3 += bfhi(u7);
        }
        for (; e < e1; ++e) {
            unsigned int u = h1h32[(size_t)srcs[e] * 64 + lane];
            ax0 += bflo(u); ay0 += bfhi(u);
        }
        float ax = (ax0 + ax1) + (ax2 + ax3);
        float ay = (ay0 + ay1) + (ay2 + ay3);
        int d = e1 - e0;
        float rd = (d > 0) ? (1.0f / (float)d) : 1.0f;
        unsigned int p = (unsigned int)f2bf(ax * rd) | ((unsigned int)f2bf(ay * rd) << 16);
        *reinterpret_cast<unsigned int*>(&A[nl][2 * lane]) = p;
    }
    __syncthreads();

    const int r15 = lane & 15, g4 = lane >> 4;
    const int n0 = wid * 32;
    f32x4 acc[2][2] = {};
    for (int kk = 0; kk < 8; ++kk) {
        short8 b0 = *reinterpret_cast<const short8*>(Bp2 + (((kk * 128 + n0 + r15) * 4 + g4) << 3));
        short8 b1 = *reinterpret_cast<const short8*>(Bp2 + (((kk * 128 + n0 + 16 + r15) * 4 + g4) << 3));
        #pragma unroll
        for (int mt = 0; mt < 2; ++mt) {
            short8 a = *reinterpret_cast<const short8*>(&A[mt * 16 + r15][kk * 32 + g4 * 8]);
            acc[mt][0] = __builtin_amdgcn_mfma_f32_16x16x32_bf16(a, b0, acc[mt][0], 0, 0, 0);
            acc[mt][1] = __builtin_amdgcn_mfma_f32_16x16x32_bf16(a, b1, acc[mt][1], 0, 0, 0);
        }
    }
    __syncthreads();
    float* h2L = reinterpret_cast<float*>(&A[0][0]);   // [32][132]
    #pragma unroll
    for (int mt = 0; mt < 2; ++mt)
        #pragma unroll
        for (int nt = 0; nt < 2; ++nt) {
            int col = n0 + nt * 16 + r15;
            float bb = b[col];
            #pragma unroll
            for (int reg = 0; reg < 4; ++reg) {
                int row = mt * 16 + g4 * 4 + reg;
                h2L[row * 132 + col] = fmaxf(acc[mt][nt][reg] + bb, 0.0f);
            }
        }
    __syncthreads();

    for (int t = tid; t < 352; t += 256) {       // heads
        int node = t / 11, o = t - node * 11;
        const float* h2 = &h2L[node * 132];
        if (o < 3) {
            float s = bh[o];
            for (int k = 0; k < 128; ++k) s += h2[k] * Wh[k * 3 + o];
            out1[(size_t)(tile + node) * 3 + o] = s;
        } else {
            int m = o - 3;
            float s = bm[m];
            for (int k = 0; k < 128; ++k) s += h2[k] * Wm[k * 8 + m];
            out2[(size_t)(tile + node) * 8 + m] = s;
        }
    }
}

extern "C" void kernel_launch(void* const* d_in, const int* in_sizes, int n_in,
                              void* d_out, int out_size, void* d_ws, size_t ws_size,
                              hipStream_t stream) {
    const float* x   = (const float*)d_in[0];
    const int*   ei  = (const int*)d_in[1];
    const int*   src = ei;
    const int*   dst = ei + N_EDGES;
    const float* Wl1 = (const float*)d_in[2];
    const float* Wr1 = (const float*)d_in[3];
    const float* b1  = (const float*)d_in[4];
    const float* Wl2 = (const float*)d_in[5];
    const float* Wr2 = (const float*)d_in[6];
    const float* b2  = (const float*)d_in[7];
    const float* Wh  = (const float*)d_in[8];
    const float* bh  = (const float*)d_in[9];
    const float* Wm  = (const float*)d_in[10];
    const float* bm  = (const float*)d_in[11];

    float* out1 = (float*)d_out;                   // [N,3]
    float* out2 = out1 + (size_t)N_NODES * 3;      // [N,8]

    char* ws = (char*)d_ws;
    int*   deg      = (int*)(ws);                           // 100000 ints
    int*   rowstart = (int*)(ws + (512 << 10));             // 100001 ints
    int*   bsum     = (int*)(ws + (960 << 10));             // 98 ints
    int*   boff     = (int*)(ws + (1024 << 10));            // 98 ints
    int*   ccur     = (int*)(ws + (1088 << 10));            // 196 ints
    unsigned int* pairs = (unsigned int*)(ws + (1536 << 10)); // 1.6M u32 (6.4MB)
    int*   srcs     = (int*)(ws + (8192 << 10));            // 1.6M ints (6.4MB)
    unsigned short* xh  = (unsigned short*)(ws + (15360 << 10)); // 6.4M bf16 (12.8MB)
    unsigned short* h1h = (unsigned short*)(ws + (28672 << 10)); // 12.8M bf16 (25.6MB)
    unsigned short* Bp1 = (unsigned short*)(ws + (54784 << 10)); // 16384 bf16 (32KB)
    unsigned short* Bp2 = (unsigned short*)(ws + (54848 << 10)); // 32768 bf16 (64KB)

    const int NSCAN = (N_NODES + 1023) / 1024;              // 98
    const int NBKT_BLKS = (N_EDGES + 256 * EPT - 1) / (256 * EPT);  // 391

    hipMemsetAsync(deg, 0, N_NODES * sizeof(int), stream);
    k_cast_hist<<<6250, 256, 0, stream>>>(x, xh, dst, deg);
    k_part_scan<<<NSCAN, 1024, 0, stream>>>(deg, rowstart, bsum);
    k_scan_bsum<<<1, 128, 0, stream>>>(bsum, boff, rowstart, NSCAN);
    k_add_off<<<NSCAN, 1024, 0, stream>>>(boff, rowstart);
    k_init_ccur<<<1, 256, 0, stream>>>(rowstart, ccur);
    k_bucket<<<NBKT_BLKS, 256, 0, stream>>>(src, dst, ccur, pairs);
    k_scatter_csr<<<NBUCK, 256, 0, stream>>>(rowstart, pairs, srcs);
    k_pack<<<192, 256, 0, stream>>>(Wl1, Wr1, Wl2, Wr2, Bp1, Bp2);

    k_layer1<<<3125, 256, 0, stream>>>(xh, rowstart, srcs, Bp1, b1, h1h);
    k_layer2<<<3125, 256, 0, stream>>>((const unsigned int*)h1h, rowstart, srcs,
                                       Bp2, b2, Wh, bh, Wm, bm, out1, out2);
}